// Round 20
// baseline (129.661 us; speedup 1.0000x reference)
//
#include <hip/hip_runtime.h>
#include <math.h>

#define NB 2
#define NH 16
#define NT 2048
#define ND 64
#define NC 1024
#define L2E 1.44269504f

typedef __attribute__((ext_vector_type(4))) float f32x4;
typedef __attribute__((ext_vector_type(8))) short short8;
typedef __attribute__((ext_vector_type(4))) short short4_t;
typedef __attribute__((ext_vector_type(8))) unsigned short ushort8;
typedef __attribute__((ext_vector_type(4))) unsigned short ushort4_t;

// per-head attention window in 64-tiles: 1 + ceil(D_h/64), D_h = 40/slL2_h.
__device__ const int WTAB[16] = {2,2,3,3,4,5,6,8,11,15,21,29,32,32,32,32};

#define GLOAD_LDS(gp, lp)                                                \
    __builtin_amdgcn_global_load_lds(                                    \
        (const __attribute__((address_space(1))) void*)(gp),             \
        (__attribute__((address_space(3))) void*)(lp), 16, 0, 0)

// storage permutation: position p holds logical index
// sigma(p) = 4*((p>>3)&3) + (p&3) + 16*((p>>2)&1) + 32*(p>>5)
// fragment (g,h) = one contiguous 16B at ushort offset 8g+32h.
__device__ __forceinline__ int sigma_p(int p) {
    return 4 * ((p >> 3) & 3) + (p & 3) + 16 * ((p >> 2) & 1) + 32 * (p >> 5);
}

__device__ __forceinline__ unsigned short f2bf(float f) {
    unsigned u = __builtin_bit_cast(unsigned, f);
    unsigned r = (u + 0x7FFFu + ((u >> 16) & 1u)) >> 16;
    return (unsigned short)r;
}

__device__ __forceinline__ float bf2f(unsigned short s) {
    return __builtin_bit_cast(float, (unsigned)s << 16);
}

__device__ __forceinline__ unsigned cvtpk_bf16(float lo, float hi) {
    unsigned r;
    asm("v_cvt_pk_bf16_f32 %0, %1, %2" : "=v"(r) : "v"(lo), "v"(hi));
    return r;
}

__device__ __forceinline__ f32x4 mfma16(short8 a, short8 b, f32x4 c) {
    return __builtin_amdgcn_mfma_f32_16x16x32_bf16(a, b, c, 0, 0, 0);
}

// split-fragment load (out_proj path, logical order)
__device__ __forceinline__ short8 frag_load(const unsigned short* rowp, int g, int half) {
    short8 v;
    short4_t lo = *(const short4_t*)(rowp + 4 * g + 32 * half);
    short4_t hi = *(const short4_t*)(rowp + 4 * g + 16 + 32 * half);
    #pragma unroll
    for (int j = 0; j < 4; ++j) { v[j] = lo[j]; v[4 + j] = hi[j]; }
    return v;
}

// sigma-stored global row: fragment = single 16B load
__device__ __forceinline__ short8 frag_g(const unsigned short* rowp, int g, int half) {
    return *(const short8*)(rowp + 8 * g + 32 * half);
}

// sigma-stored LDS tile, 128B rows (64 k): chunk XOR by (row&7)
__device__ __forceinline__ short8 frag_swz128(const unsigned short* tile, int row, int g, int half) {
    const char* p = (const char*)tile + row * 128 + (((g + 4 * half) ^ (row & 7)) << 4);
    return *(const short8*)p;
}

// sigma-stored LDS tile, 64B rows (32 k): chunk XOR by ((row>>1)&3)
__device__ __forceinline__ short8 frag_swz32(const unsigned short* tile, int row, int g) {
    const char* p = (const char*)tile + row * 64 + (((g ^ ((row >> 1) & 3))) << 4);
    return *(const short8*)p;
}

// ---------------------------------------------------------------------------
// x f32 -> bf16 with sigma permutation of each 64-dim block
// ---------------------------------------------------------------------------
__global__ __launch_bounds__(256) void cvt_x(const float* __restrict__ src,
                                             unsigned short* __restrict__ dst, int n4) {
    int i = blockIdx.x * 256 + threadIdx.x;
    if (i >= n4) return;
    const int blk = i >> 4, c4 = i & 15;
    const int gg = (c4 >> 1) & 3, bb = c4 & 1, hh = c4 >> 3;
    f32x4 v = ((const f32x4*)src)[blk * 16 + gg + 4 * bb + 8 * hh];
    ushort4_t o;
    #pragma unroll
    for (int j = 0; j < 4; ++j) o[j] = f2bf(v[j]);
    ((ushort4_t*)dst)[i] = o;
}

// ---------------------------------------------------------------------------
// weights: z=0..2 -> wq/wk/wv f32 [k][n] -> bf16 [n][k-sigma];
// z=3 (x-block 0 only) -> wo f32 [64][1024] -> bf16 [n][k] logical.
// ---------------------------------------------------------------------------
__global__ __launch_bounds__(256) void cvtW(const float* __restrict__ w0,
                                            const float* __restrict__ w1,
                                            const float* __restrict__ w2,
                                            const float* __restrict__ w3,
                                            unsigned short* __restrict__ Wt_all,
                                            unsigned short* __restrict__ Wot) {
    __shared__ __align__(16) float T[64][68];
    const int z = blockIdx.z;
    const int tid = threadIdx.x;
    if (z == 3) {
        if (blockIdx.x != 0) return;
        const int n0 = blockIdx.y * 64;
        #pragma unroll
        for (int p = 0; p < 4; ++p) {
            int r = 16 * p + (tid >> 4);
            int c = (tid & 15) * 4;
            *(f32x4*)&T[r][c] = *(const f32x4*)&w3[(size_t)r * NC + n0 + c];
        }
        __syncthreads();
        const int nr = tid >> 2, kc = (tid & 3) * 16;
        ushort8 o0, o1;
        #pragma unroll
        for (int j = 0; j < 8; ++j) { o0[j] = f2bf(T[kc + j][nr]); o1[j] = f2bf(T[kc + 8 + j][nr]); }
        unsigned short* q = Wot + (size_t)(n0 + nr) * ND + kc;
        *(ushort8*)q       = o0;
        *(ushort8*)(q + 8) = o1;
        return;
    }
    const float* W = (z == 0) ? w0 : ((z == 1) ? w1 : w2);
    unsigned short* Wt = Wt_all + (size_t)z * NC * NC;
    const int k0 = blockIdx.x * 64, n0 = blockIdx.y * 64;
    #pragma unroll
    for (int p = 0; p < 4; ++p) {
        int r = 16 * p + (tid >> 4);
        int c = (tid & 15) * 4;
        *(f32x4*)&T[r][c] = *(const f32x4*)&W[(size_t)(k0 + r) * NC + n0 + c];
    }
    __syncthreads();
    const int nr = tid >> 2, kc = (tid & 3) * 16;
    ushort8 o0, o1;
    #pragma unroll
    for (int j = 0; j < 8; ++j) o0[j] = f2bf(T[sigma_p(kc + j)][nr]);
    #pragma unroll
    for (int j = 0; j < 8; ++j) o1[j] = f2bf(T[sigma_p(kc + 8 + j)][nr]);
    unsigned short* q = Wt + (size_t)(n0 + nr) * NC + k0 + kc;
    *(ushort8*)q       = o0;
    *(ushort8*)(q + 8) = o1;
}

// ---------------------------------------------------------------------------
// bf16 MFMA GEMM, 128x128 tile, 4 waves, K-step 32, NBUF=3 COUNTED pipeline.
// Single launch for Q,K,V. Q/K -> sigma-d [bh][t][d']; V -> Vt[bh][d][t-sigma].
// ---------------------------------------------------------------------------
__global__ __launch_bounds__(256, 3) void gemm_qkv(const unsigned short* __restrict__ Xh,
                                                   const unsigned short* __restrict__ Wt_all,
                                                   unsigned short* __restrict__ qk_dst,
                                                   unsigned short* __restrict__ Vt) {
    __shared__ __align__(16) unsigned short Xs[3][4096];   // [buf][128 rows x 32 k]
    __shared__ __align__(16) unsigned short Ws[3][4096];
    const int tid = threadIdx.x;
    const int lane = tid & 63, w = tid >> 6;
    const int g = lane >> 4, l15 = lane & 15;
    const int wr = w >> 1, wc = w & 1;
    const int m0 = blockIdx.x * 128;
    const int which = blockIdx.y >> 3;
    const int n0 = (blockIdx.y & 7) * 128;
    const unsigned short* Wt = Wt_all + (size_t)which * NC * NC;

    const int sr[2] = { (0 * 256 + w * 64 + lane) >> 2, (1 * 256 + w * 64 + lane) >> 2 };
    const int sc[2] = { ((0 * 256 + w * 64 + lane) & 3) ^ ((sr[0] >> 1) & 3),
                        ((1 * 256 + w * 64 + lane) & 3) ^ ((sr[1] >> 1) & 3) };

    f32x4 acc[4][4] = {};

    auto stage = [&](int buf, int kt) {
        const size_t kb = (size_t)kt * 64;
        #pragma unroll
        for (int i = 0; i < 2; ++i) {
            const char* xs = (const char*)Xh + (size_t)(m0 + sr[i]) * 2048 + kb + (sc[i] << 4);
            GLOAD_LDS(xs, (char*)&Xs[buf][(i * 256 + w * 64) * 8]);
            const char* ws = (const char*)Wt + (size_t)(n0 + sr[i]) * 2048 + kb + (sc[i] << 4);
            GLOAD_LDS(ws, (char*)&Ws[buf][(i * 256 + w * 64) * 8]);
        }
    };

    stage(0, 0);
    stage(1, 1);
    int cur = 0, nxt = 2;

    for (int kt = 0; kt < 32; ++kt) {
        if (kt < 31) asm volatile("s_waitcnt vmcnt(4)" ::: "memory");
        else         asm volatile("s_waitcnt vmcnt(0)" ::: "memory");
        __builtin_amdgcn_s_barrier();
        if (kt + 2 < 32) stage(nxt, kt + 2);
        short8 a[4], b[4];
        #pragma unroll
        for (int mr = 0; mr < 4; ++mr)
            a[mr] = frag_swz32(Xs[cur], 64 * wr + 16 * mr + l15, g);
        #pragma unroll
        for (int nc = 0; nc < 4; ++nc)
            b[nc] = frag_swz32(Ws[cur], 64 * wc + 16 * nc + l15, g);
        __builtin_amdgcn_s_setprio(1);
        #pragma unroll
        for (int mr = 0; mr < 4; ++mr)
            #pragma unroll
            for (int nc = 0; nc < 4; ++nc)
                acc[mr][nc] = mfma16(a[mr], b[nc], acc[mr][nc]);
        __builtin_amdgcn_s_setprio(0);
        cur = (cur == 2) ? 0 : cur + 1;
        nxt = (nxt == 2) ? 0 : nxt + 1;
    }

    if (which < 2) {
        unsigned short* dst = qk_dst + (size_t)which * (NB * NH * NT * ND);
        #pragma unroll
        for (int mr = 0; mr < 4; ++mr) {
            #pragma unroll
            for (int nc = 0; nc < 4; ++nc) {
                const int n = n0 + 64 * wc + 16 * nc + l15;
                const int hh = n >> 6;
                const int dd = 32 * (nc >> 1) + 8 * (l15 >> 2) + 4 * (nc & 1) + (l15 & 3);
                #pragma unroll
                for (int r = 0; r < 4; ++r) {
                    const int m = m0 + 64 * wr + 16 * mr + 4 * g + r;
                    const int bb = m >> 11, tt = m & (NT - 1);
                    dst[(((size_t)bb * NH + hh) * NT + tt) * ND + dd] = f2bf(acc[mr][nc][r]);
                }
            }
        }
    } else {
        #pragma unroll
        for (int mr = 0; mr < 4; ++mr) {
            const int m = m0 + 64 * wr + 16 * mr + 4 * g;
            const int bb = m >> 11, tt = m & (NT - 1);
            const int tbase = (tt & ~63) + 32 * (mr >> 1) + 8 * g + 4 * (mr & 1);
            #pragma unroll
            for (int nc = 0; nc < 4; ++nc) {
                const int n = n0 + 64 * wc + 16 * nc + l15;
                const int hh = n >> 6, dd = n & 63;
                ushort4_t o;
                #pragma unroll
                for (int r = 0; r < 4; ++r) o[r] = f2bf(acc[mr][nc][r]);
                *(ushort4_t*)&Vt[(((size_t)bb * NH + hh) * ND + dd) * NT + tbase] = o;
            }
        }
    }
}

// ---------------------------------------------------------------------------
// Pass A (windowed, q-PARITY split): block (j, bh, par) sums exp2 over
// q-tiles qt ≡ par (mod 2) in [j, j+Wt). Raw partial sums to Lc2[par].
// Zero-work blocks write zeros (other parity holds the diagonal > 0).
// ---------------------------------------------------------------------------
__global__ __launch_bounds__(256, 4) void colstats(const unsigned short* __restrict__ Qh,
                                                   const unsigned short* __restrict__ Kh,
                                                   float* __restrict__ Lc2) {
    __shared__ __align__(16) unsigned short Qs[3][4096];
    const int tid = threadIdx.x;
    const int lane = tid & 63, w = tid >> 6;
    const int g = lane >> 4, l15 = lane & 15;
    const int subrow = lane >> 3;
    const int src_off = (((lane & 7) ^ subrow) << 4);
    const int lin = blockIdx.x + 32 * blockIdx.y;       // 0..2047
    const int par = lin & 1;
    const int rest = lin >> 1;                          // 0..1023
    const int xcd = rest & 7, idx = rest >> 3;          // idx 0..127
    const int slot = idx & 3;
    const int j = idx >> 2;                             // 0..31, heavy (small j) first
    const int hh = (slot & 1) ? (15 - xcd) : xcd;
    const int bh = ((slot >> 1) << 4) + hh;
    const float slL2 = exp2f(-0.5f * (float)(hh + 1)) * L2E;
    const float C1 = 0.125f * L2E;
    const float s16 = 16.f * slL2;
    const int Wt = WTAB[hh];
    const int qtend = min(32, j + Wt);
    const int qt0 = j + ((par ^ j) & 1);                // first qt >= j with qt%2 == par

    const unsigned short* kr = Kh + ((size_t)bh * NT + 64 * j + 16 * w + l15) * ND;
    const short8 ak0 = frag_g(kr, g, 0), ak1 = frag_g(kr, g, 1);
    const int k0 = 64 * j + 16 * w + 4 * g;

    const char* Qbase = (const char*)(Qh + (size_t)bh * NT * ND);
    auto stage = [&](int buf, int qt) {
        const char* qs = Qbase + (size_t)(64 * qt + 16 * w + subrow) * 128 + src_off;
        char* qd = (char*)&Qs[buf][16 * w * 64];
        GLOAD_LDS(qs, qd);
        GLOAD_LDS(qs + 1024, qd + 1024);
    };

    f32x4 acc = {};
    float rs[4];
    #pragma unroll
    for (int r = 0; r < 4; ++r) rs[r] = (float)r * slL2;

    if (qt0 < qtend) stage(0, qt0);
    if (qt0 + 2 < qtend) stage(1, qt0 + 2);
    int cur = 0, nxt = 2;

    for (int qt = qt0; qt < qtend; qt += 2) {
        if (qt + 2 < qtend) asm volatile("s_waitcnt vmcnt(2)" ::: "memory");
        else                asm volatile("s_waitcnt vmcnt(0)" ::: "memory");
        __builtin_amdgcn_s_barrier();
        if (qt + 4 < qtend) stage(nxt, qt + 4);
        const unsigned short* tile = Qs[cur];
        short8 qf[8];
        #pragma unroll
        for (int q4 = 0; q4 < 4; ++q4) {
            qf[2 * q4]     = frag_swz128(tile, 16 * q4 + l15, g, 0);
            qf[2 * q4 + 1] = frag_swz128(tile, 16 * q4 + l15, g, 1);
        }
        float b0 = (float)(k0 - 64 * qt - l15) * slL2;
        const bool mask = (qt == j);
        #pragma unroll
        for (int q4 = 0; q4 < 4; ++q4) {
            f32x4 d = {};
            __builtin_amdgcn_s_setprio(1);
            d = mfma16(ak0, qf[2 * q4], d);
            d = mfma16(ak1, qf[2 * q4 + 1], d);
            __builtin_amdgcn_s_setprio(0);
            #pragma unroll
            for (int r = 0; r < 4; ++r) {
                float e = exp2f(fmaf(d[r], C1, b0 + rs[r]));
                if (mask && (16 * q4 + l15 < 16 * w + 4 * g + r)) e = 0.f;
                acc[r] += e;
            }
            b0 -= s16;
        }
        cur = (cur == 2) ? 0 : cur + 1;
        nxt = (nxt == 2) ? 0 : nxt + 1;
    }
    #pragma unroll
    for (int off = 1; off <= 8; off <<= 1)
        #pragma unroll
        for (int r = 0; r < 4; ++r) acc[r] += __shfl_xor(acc[r], off);
    if (l15 == 0) {
        float* Lp = Lc2 + (size_t)(par * 32 + bh) * NT;
        #pragma unroll
        for (int r = 0; r < 4; ++r) Lp[k0 + r] = acc[r];
    }
}

// ---------------------------------------------------------------------------
// scale_v: Vt[bh][d][tpos] /= (Sa[t] + Sb[t]) in place (two parity halves).
// ---------------------------------------------------------------------------
__global__ __launch_bounds__(256) void scale_v(const float* __restrict__ Lc2,
                                               unsigned short* __restrict__ Vt) {
    const int i = blockIdx.x * 256 + threadIdx.x;     // ushort4 units
    const int bh = i >> 15;
    const int tpos4 = (i & 511) * 4;
    const int tlog = (tpos4 & ~63) + sigma_p(tpos4 & 63);
    f32x4 a = *(const f32x4*)(Lc2 + (size_t)bh * NT + tlog);
    f32x4 b = *(const f32x4*)(Lc2 + (size_t)(32 + bh) * NT + tlog);
    ushort4_t v = ((const ushort4_t*)Vt)[i];
    ushort4_t o;
    #pragma unroll
    for (int j = 0; j < 4; ++j)
        o[j] = f2bf(bf2f(v[j]) / (a[j] + b[j]));
    ((ushort4_t*)Vt)[i] = o;
}

// ---------------------------------------------------------------------------
// Pass B (windowed, k-PARITY split): block (j, bh, par) does k-tiles
// kt ≡ par (mod 2) in [j-Wt+1, j]; V pre-scaled; NBUF=3 counted pipeline.
// Parity 0 -> att, parity 1 -> att2 (both bf16; zero-work blocks write 0).
// ---------------------------------------------------------------------------
__global__ __launch_bounds__(256, 3) void attn_pv(const unsigned short* __restrict__ Qh,
                                                  const unsigned short* __restrict__ Kh,
                                                  const unsigned short* __restrict__ Vt,
                                                  unsigned short* __restrict__ att,
                                                  unsigned short* __restrict__ att2) {
    __shared__ __align__(16) unsigned short Ks[3][4096];
    __shared__ __align__(16) unsigned short Vs[3][4096];
    const int tid = threadIdx.x;
    const int lane = tid & 63, w = tid >> 6;
    const int g = lane >> 4, l15 = lane & 15;
    const int subrow = lane >> 3;
    const int src_off = (((lane & 7) ^ subrow) << 4);
    const int lin = blockIdx.x + 32 * blockIdx.y;       // 0..2047
    const int par = lin & 1;
    const int rest = lin >> 1;
    const int xcd = rest & 7, idx = rest >> 3;
    const int slot = idx & 3;
    const int j = 31 - (idx >> 2);                      // heavy (large j) first
    const int hh = (slot & 1) ? (15 - xcd) : xcd;
    const int bh = ((slot >> 1) << 4) + hh;
    const int bb = bh >> 4;
    const float slL2 = exp2f(-0.5f * (float)(hh + 1)) * L2E;
    const float C1 = 0.125f * L2E;
    const float s16 = 16.f * slL2;
    const int Wt = WTAB[hh];
    const int ktmin = max(0, j - Wt + 1);
    const int kt0 = ktmin + ((par ^ ktmin) & 1);        // first kt >= ktmin with kt%2 == par

    const int q = 64 * j + 16 * w + l15;
    short8 bq0, bq1;
    {
        const unsigned short* qr = Qh + ((size_t)bh * NT + q) * ND;
        bq0 = frag_g(qr, g, 0);
        bq1 = frag_g(qr, g, 1);
    }
    float rs[4];
    #pragma unroll
    for (int r = 0; r < 4; ++r) rs[r] = (float)r * slL2;

    auto stageKV = [&](int buf, int K0) {
        const char* ksrc = (const char*)Kh + (size_t)((size_t)bh * NT + K0 + 16 * w + subrow) * 128 + src_off;
        char* kdst = (char*)&Ks[buf][16 * w * 64];
        GLOAD_LDS(ksrc, kdst);
        GLOAD_LDS(ksrc + 1024, kdst + 1024);
        const char* vsrc = (const char*)Vt + ((((size_t)bh * ND + 16 * w + subrow) * NT + K0) << 1) + src_off;
        char* vdst = (char*)&Vs[buf][16 * w * 64];
        GLOAD_LDS(vsrc, vdst);
        GLOAD_LDS(vsrc + 8 * NT * 2, vdst + 1024);
    };

    if (kt0 <= j) stageKV(0, 64 * kt0);
    if (kt0 + 2 <= j) stageKV(1, 64 * (kt0 + 2));
    int cur = 0, nxt = 2;

    f32x4 o[4] = {};

    for (int kt = kt0; kt <= j; kt += 2) {
        if (kt + 2 <= j) asm volatile("s_waitcnt vmcnt(4)" ::: "memory");
        else             asm volatile("s_waitcnt vmcnt(0)" ::: "memory");
        __builtin_amdgcn_s_barrier();
        if (kt + 4 <= j) stageKV(nxt, 64 * (kt + 4));
        const int K0 = 64 * kt;
        short8 kf[8], vf[8];
        #pragma unroll
        for (int s4 = 0; s4 < 4; ++s4) {
            kf[2 * s4]     = frag_swz128(Ks[cur], 16 * s4 + l15, g, 0);
            kf[2 * s4 + 1] = frag_swz128(Ks[cur], 16 * s4 + l15, g, 1);
            vf[2 * s4]     = frag_swz128(Vs[cur], 16 * s4 + l15, g, 0);
            vf[2 * s4 + 1] = frag_swz128(Vs[cur], 16 * s4 + l15, g, 1);
        }
        f32x4 pacc[4];
        __builtin_amdgcn_s_setprio(1);
        #pragma unroll
        for (int s4 = 0; s4 < 4; ++s4) {
            f32x4 d = {};
            d = mfma16(kf[2 * s4], bq0, d);
            d = mfma16(kf[2 * s4 + 1], bq1, d);
            pacc[s4] = d;
        }
        __builtin_amdgcn_s_setprio(0);
        union { unsigned u[4]; short8 s; } pa[2];
        float b = (float)(K0 + 4 * g - q) * slL2;
        const bool mask = (kt == j);
        #pragma unroll
        for (int s4 = 0; s4 < 4; ++s4) {
            float p[4];
            #pragma unroll
            for (int r = 0; r < 4; ++r)
                p[r] = exp2f(fmaf(pacc[s4][r], C1, b + rs[r]));
            if (mask) {
                #pragma unroll
                for (int r = 0; r < 4; ++r)
                    if (K0 + 16 * s4 + 4 * g + r > q) p[r] = 0.f;
            }
            pa[s4 >> 1].u[2 * (s4 & 1)]     = cvtpk_bf16(p[0], p[1]);
            pa[s4 >> 1].u[2 * (s4 & 1) + 1] = cvtpk_bf16(p[2], p[3]);
            b += s16;
        }
        __builtin_amdgcn_s_setprio(1);
        #pragma unroll
        for (int n = 0; n < 4; ++n) {
            o[n] = mfma16(pa[0].s, vf[2 * n], o[n]);
            o[n] = mfma16(pa[1].s, vf[2 * n + 1], o[n]);
        }
        __builtin_amdgcn_s_setprio(0);
        cur = (cur == 2) ? 0 : cur + 1;
        nxt = (nxt == 2) ? 0 : nxt + 1;
    }
    // partial output, [b][t][h][d] bf16 (zero if this parity had no tiles)
    unsigned short* dst = (par == 0) ? att : att2;
    #pragma unroll
    for (int n = 0; n < 4; ++n) {
        #pragma unroll
        for (int r = 0; r < 4; ++r) {
            dst[(((size_t)bb * NT + 64 * j + 16 * w + 4 * g + r) * NH + hh) * ND + 16 * n + l15] = f2bf(o[n][r]);
        }
    }
}

// ---------------------------------------------------------------------------
// A[row][d] = bf16( sum_h att[row][h][d] + att2[row][h][d] )
// ---------------------------------------------------------------------------
__global__ __launch_bounds__(256) void headsum(const unsigned short* __restrict__ att,
                                               const unsigned short* __restrict__ att2,
                                               unsigned short* __restrict__ A) {
    const int row = blockIdx.x * 16 + (threadIdx.x >> 4);
    const int d0 = (threadIdx.x & 15) * 4;
    const unsigned short* p  = att  + (size_t)row * (NH * ND) + d0;
    const unsigned short* p2 = att2 + (size_t)row * (NH * ND) + d0;
    f32x4 s = {};
    #pragma unroll
    for (int h = 0; h < NH; ++h) {
        ushort4_t v  = *(const ushort4_t*)(p + h * ND);
        ushort4_t v2 = *(const ushort4_t*)(p2 + h * ND);
        #pragma unroll
        for (int jj = 0; jj < 4; ++jj) s[jj] += bf2f(v[jj]) + bf2f(v2[jj]);
    }
    ushort4_t o;
    #pragma unroll
    for (int jj = 0; jj < 4; ++jj) o[jj] = f2bf(s[jj]);
    *(ushort4_t*)&A[(size_t)row * ND + d0] = o;
}

// ---------------------------------------------------------------------------
// out[m,n] = x[m,n] + (A @ wo)[m,n]  via MFMA (logical-order fragments)
// ---------------------------------------------------------------------------
__global__ __launch_bounds__(256) void out_proj(const float* __restrict__ x,
                                                const unsigned short* __restrict__ A,
                                                const unsigned short* __restrict__ Wot,
                                                float* __restrict__ out) {
    const int tid = threadIdx.x;
    const int lane = tid & 63, w = tid >> 6;
    const int g = lane >> 4, l15 = lane & 15;
    const int m0 = blockIdx.x * 64, n0 = blockIdx.y * 64;

    const unsigned short* ar = A + (size_t)(m0 + 16 * w + l15) * ND;
    short8 a0 = frag_load(ar, g, 0);
    short8 a1 = frag_load(ar, g, 1);

    f32x4 acc[4] = {};
    #pragma unroll
    for (int ns = 0; ns < 4; ++ns) {
        const unsigned short* br = Wot + (size_t)(n0 + 16 * ns + l15) * ND;
        acc[ns] = mfma16(a0, frag_load(br, g, 0), acc[ns]);
        acc[ns] = mfma16(a1, frag_load(br, g, 1), acc[ns]);
    }
    #pragma unroll
    for (int ns = 0; ns < 4; ++ns) {
        #pragma unroll
        for (int r = 0; r < 4; ++r) {
            int m = m0 + 16 * w + 4 * g + r;
            int n = n0 + 16 * ns + l15;
            out[(size_t)m * NC + n] = x[(size_t)m * NC + n] + acc[ns][r];
        }
    }
}

// ---------------------------------------------------------------------------
extern "C" void kernel_launch(void* const* d_in, const int* in_sizes, int n_in,
                              void* d_out, int out_size, void* d_ws, size_t ws_size,
                              hipStream_t stream) {
    const float* x  = (const float*)d_in[0];
    const float* wq = (const float*)d_in[1];
    const float* wk = (const float*)d_in[2];
    const float* wv = (const float*)d_in[3];
    const float* wo = (const float*)d_in[4];
    float* out = (float*)d_out;

    const size_t MB = 1u << 20;
    const size_t KB = 1u << 10;
    unsigned char* w8 = (unsigned char*)d_ws;
    unsigned short* Xh   = (unsigned short*)(w8);               //  8 MB (sigma k)
    unsigned short* Wta  = (unsigned short*)(w8 + 8 * MB);      //  6 MB [3][n][k-sigma]
    unsigned short* Qh   = (unsigned short*)(w8 + 16 * MB);     //  8 MB (sigma d)
    unsigned short* Kh   = (unsigned short*)(w8 + 24 * MB);     //  8 MB (sigma d)
    unsigned short* Vt   = (unsigned short*)(w8 + 32 * MB);     //  8 MB (sigma t)
    unsigned short* att  = (unsigned short*)(w8 + 40 * MB);     //  8 MB bf16 (parity 0)
    unsigned short* att2 = (unsigned short*)(w8 + 48 * MB);     //  8 MB bf16 (parity 1)
    float*          Lc2  = (float*)(w8 + 56 * MB);              // 512 KB (2 halves)
    unsigned short* A    = (unsigned short*)(w8 + 56 * MB + 512 * KB);  // 512 KB
    unsigned short* Wot  = (unsigned short*)(w8 + 57 * MB);     // 128 KB

    cvt_x<<<(NB * NT * NC) / 1024, 256, 0, stream>>>(x, Xh, (NB * NT * NC) / 4);
    cvtW<<<dim3(16, 16, 4), 256, 0, stream>>>(wq, wk, wv, wo, Wta, Wot);

    gemm_qkv<<<dim3(32, 24), 256, 0, stream>>>(Xh, Wta, Qh, Vt);

    colstats<<<dim3(32, 64), 256, 0, stream>>>(Qh, Kh, Lc2);
    scale_v<<<(32 * ND * NT / 4) / 256, 256, 0, stream>>>(Lc2, Vt);
    attn_pv<<<dim3(32, 64), 256, 0, stream>>>(Qh, Kh, Vt, att, att2);

    headsum<<<(NB * NT) / 16, 256, 0, stream>>>(att, att2, A);
    out_proj<<<dim3(64, 16), 256, 0, stream>>>(x, A, Wot, out);
}

// Round 21
// 127.441 us; speedup vs baseline: 1.0174x; 1.0174x over previous
//
#include <hip/hip_runtime.h>
#include <math.h>

#define NB 2
#define NH 16
#define NT 2048
#define ND 64
#define NC 1024
#define L2E 1.44269504f

typedef __attribute__((ext_vector_type(4))) float f32x4;
typedef __attribute__((ext_vector_type(8))) short short8;
typedef __attribute__((ext_vector_type(4))) short short4_t;
typedef __attribute__((ext_vector_type(8))) unsigned short ushort8;
typedef __attribute__((ext_vector_type(4))) unsigned short ushort4_t;

// per-head attention window in 64-tiles: 1 + ceil(D_h/64), D_h = 40/slL2_h.
__device__ const int WTAB[16] = {2,2,3,3,4,5,6,8,11,15,21,29,32,32,32,32};

#define GLOAD_LDS(gp, lp)                                                \
    __builtin_amdgcn_global_load_lds(                                    \
        (const __attribute__((address_space(1))) void*)(gp),             \
        (__attribute__((address_space(3))) void*)(lp), 16, 0, 0)

// storage permutation: position p holds logical index
// sigma(p) = 4*((p>>3)&3) + (p&3) + 16*((p>>2)&1) + 32*(p>>5)
// fragment (g,h) = one contiguous 16B at ushort offset 8g+32h.
__device__ __forceinline__ int sigma_p(int p) {
    return 4 * ((p >> 3) & 3) + (p & 3) + 16 * ((p >> 2) & 1) + 32 * (p >> 5);
}

__device__ __forceinline__ unsigned short f2bf(float f) {
    unsigned u = __builtin_bit_cast(unsigned, f);
    unsigned r = (u + 0x7FFFu + ((u >> 16) & 1u)) >> 16;
    return (unsigned short)r;
}

__device__ __forceinline__ float bf2f(unsigned short s) {
    return __builtin_bit_cast(float, (unsigned)s << 16);
}

__device__ __forceinline__ unsigned cvtpk_bf16(float lo, float hi) {
    unsigned r;
    asm("v_cvt_pk_bf16_f32 %0, %1, %2" : "=v"(r) : "v"(lo), "v"(hi));
    return r;
}

__device__ __forceinline__ f32x4 mfma16(short8 a, short8 b, f32x4 c) {
    return __builtin_amdgcn_mfma_f32_16x16x32_bf16(a, b, c, 0, 0, 0);
}

// split-fragment load (out_proj path, logical order)
__device__ __forceinline__ short8 frag_load(const unsigned short* rowp, int g, int half) {
    short8 v;
    short4_t lo = *(const short4_t*)(rowp + 4 * g + 32 * half);
    short4_t hi = *(const short4_t*)(rowp + 4 * g + 16 + 32 * half);
    #pragma unroll
    for (int j = 0; j < 4; ++j) { v[j] = lo[j]; v[4 + j] = hi[j]; }
    return v;
}

// sigma-stored global row: fragment = single 16B load
__device__ __forceinline__ short8 frag_g(const unsigned short* rowp, int g, int half) {
    return *(const short8*)(rowp + 8 * g + 32 * half);
}

// sigma-stored LDS tile, 128B rows (64 k): chunk XOR by (row&7)
__device__ __forceinline__ short8 frag_swz128(const unsigned short* tile, int row, int g, int half) {
    const char* p = (const char*)tile + row * 128 + (((g + 4 * half) ^ (row & 7)) << 4);
    return *(const short8*)p;
}

// sigma-stored LDS tile, 64B rows (32 k): chunk XOR by ((row>>1)&3)
__device__ __forceinline__ short8 frag_swz32(const unsigned short* tile, int row, int g) {
    const char* p = (const char*)tile + row * 64 + (((g ^ ((row >> 1) & 3))) << 4);
    return *(const short8*)p;
}

// ---------------------------------------------------------------------------
// x f32 -> bf16 with sigma permutation of each 64-dim block
// ---------------------------------------------------------------------------
__global__ __launch_bounds__(256) void cvt_x(const float* __restrict__ src,
                                             unsigned short* __restrict__ dst, int n4) {
    int i = blockIdx.x * 256 + threadIdx.x;
    if (i >= n4) return;
    const int blk = i >> 4, c4 = i & 15;
    const int gg = (c4 >> 1) & 3, bb = c4 & 1, hh = c4 >> 3;
    f32x4 v = ((const f32x4*)src)[blk * 16 + gg + 4 * bb + 8 * hh];
    ushort4_t o;
    #pragma unroll
    for (int j = 0; j < 4; ++j) o[j] = f2bf(v[j]);
    ((ushort4_t*)dst)[i] = o;
}

// ---------------------------------------------------------------------------
// weights: z=0..2 -> wq/wk/wv f32 [k][n] -> bf16 [n][k-sigma];
// z=3 (x-block 0 only) -> wo f32 [64][1024] -> bf16 [n][k] logical.
// ---------------------------------------------------------------------------
__global__ __launch_bounds__(256) void cvtW(const float* __restrict__ w0,
                                            const float* __restrict__ w1,
                                            const float* __restrict__ w2,
                                            const float* __restrict__ w3,
                                            unsigned short* __restrict__ Wt_all,
                                            unsigned short* __restrict__ Wot) {
    __shared__ __align__(16) float T[64][68];
    const int z = blockIdx.z;
    const int tid = threadIdx.x;
    if (z == 3) {
        if (blockIdx.x != 0) return;
        const int n0 = blockIdx.y * 64;
        #pragma unroll
        for (int p = 0; p < 4; ++p) {
            int r = 16 * p + (tid >> 4);
            int c = (tid & 15) * 4;
            *(f32x4*)&T[r][c] = *(const f32x4*)&w3[(size_t)r * NC + n0 + c];
        }
        __syncthreads();
        const int nr = tid >> 2, kc = (tid & 3) * 16;
        ushort8 o0, o1;
        #pragma unroll
        for (int j = 0; j < 8; ++j) { o0[j] = f2bf(T[kc + j][nr]); o1[j] = f2bf(T[kc + 8 + j][nr]); }
        unsigned short* q = Wot + (size_t)(n0 + nr) * ND + kc;
        *(ushort8*)q       = o0;
        *(ushort8*)(q + 8) = o1;
        return;
    }
    const float* W = (z == 0) ? w0 : ((z == 1) ? w1 : w2);
    unsigned short* Wt = Wt_all + (size_t)z * NC * NC;
    const int k0 = blockIdx.x * 64, n0 = blockIdx.y * 64;
    #pragma unroll
    for (int p = 0; p < 4; ++p) {
        int r = 16 * p + (tid >> 4);
        int c = (tid & 15) * 4;
        *(f32x4*)&T[r][c] = *(const f32x4*)&W[(size_t)(k0 + r) * NC + n0 + c];
    }
    __syncthreads();
    const int nr = tid >> 2, kc = (tid & 3) * 16;
    ushort8 o0, o1;
    #pragma unroll
    for (int j = 0; j < 8; ++j) o0[j] = f2bf(T[sigma_p(kc + j)][nr]);
    #pragma unroll
    for (int j = 0; j < 8; ++j) o1[j] = f2bf(T[sigma_p(kc + 8 + j)][nr]);
    unsigned short* q = Wt + (size_t)(n0 + nr) * NC + k0 + kc;
    *(ushort8*)q       = o0;
    *(ushort8*)(q + 8) = o1;
}

// ---------------------------------------------------------------------------
// bf16 MFMA GEMM, 128x128 tile, 4 waves, K-step 32, NBUF=3 COUNTED pipeline.
// Single launch for Q,K,V. Q/K -> sigma-d [bh][t][d']; V -> Vt[bh][d][t-sigma].
// LDS 48KB -> 3 blocks/CU. Steady-state wait vmcnt(4); no drain in loop.
// ---------------------------------------------------------------------------
__global__ __launch_bounds__(256, 3) void gemm_qkv(const unsigned short* __restrict__ Xh,
                                                   const unsigned short* __restrict__ Wt_all,
                                                   unsigned short* __restrict__ qk_dst,
                                                   unsigned short* __restrict__ Vt) {
    __shared__ __align__(16) unsigned short Xs[3][4096];   // [buf][128 rows x 32 k]
    __shared__ __align__(16) unsigned short Ws[3][4096];
    const int tid = threadIdx.x;
    const int lane = tid & 63, w = tid >> 6;
    const int g = lane >> 4, l15 = lane & 15;
    const int wr = w >> 1, wc = w & 1;
    const int m0 = blockIdx.x * 128;
    const int which = blockIdx.y >> 3;
    const int n0 = (blockIdx.y & 7) * 128;
    const unsigned short* Wt = Wt_all + (size_t)which * NC * NC;

    // staging geometry: idx = i*256 + w*64 + lane; row = idx>>2; c_lds = idx&3
    const int sr[2] = { (0 * 256 + w * 64 + lane) >> 2, (1 * 256 + w * 64 + lane) >> 2 };
    const int sc[2] = { ((0 * 256 + w * 64 + lane) & 3) ^ ((sr[0] >> 1) & 3),
                        ((1 * 256 + w * 64 + lane) & 3) ^ ((sr[1] >> 1) & 3) };

    f32x4 acc[4][4] = {};

    auto stage = [&](int buf, int kt) {                    // kt = K-step index (32 k)
        const size_t kb = (size_t)kt * 64;                 // byte offset in row
        #pragma unroll
        for (int i = 0; i < 2; ++i) {
            const char* xs = (const char*)Xh + (size_t)(m0 + sr[i]) * 2048 + kb + (sc[i] << 4);
            GLOAD_LDS(xs, (char*)&Xs[buf][(i * 256 + w * 64) * 8]);
            const char* ws = (const char*)Wt + (size_t)(n0 + sr[i]) * 2048 + kb + (sc[i] << 4);
            GLOAD_LDS(ws, (char*)&Ws[buf][(i * 256 + w * 64) * 8]);
        }
    };

    stage(0, 0);
    stage(1, 1);
    int cur = 0, nxt = 2;

    for (int kt = 0; kt < 32; ++kt) {
        if (kt < 31) asm volatile("s_waitcnt vmcnt(4)" ::: "memory");
        else         asm volatile("s_waitcnt vmcnt(0)" ::: "memory");
        __builtin_amdgcn_s_barrier();
        if (kt + 2 < 32) stage(nxt, kt + 2);
        short8 a[4], b[4];
        #pragma unroll
        for (int mr = 0; mr < 4; ++mr)
            a[mr] = frag_swz32(Xs[cur], 64 * wr + 16 * mr + l15, g);
        #pragma unroll
        for (int nc = 0; nc < 4; ++nc)
            b[nc] = frag_swz32(Ws[cur], 64 * wc + 16 * nc + l15, g);
        __builtin_amdgcn_s_setprio(1);
        #pragma unroll
        for (int mr = 0; mr < 4; ++mr)
            #pragma unroll
            for (int nc = 0; nc < 4; ++nc)
                acc[mr][nc] = mfma16(a[mr], b[nc], acc[mr][nc]);
        __builtin_amdgcn_s_setprio(0);
        cur = (cur == 2) ? 0 : cur + 1;
        nxt = (nxt == 2) ? 0 : nxt + 1;
    }

    if (which < 2) {
        unsigned short* dst = qk_dst + (size_t)which * (NB * NH * NT * ND);
        #pragma unroll
        for (int mr = 0; mr < 4; ++mr) {
            #pragma unroll
            for (int nc = 0; nc < 4; ++nc) {
                const int n = n0 + 64 * wc + 16 * nc + l15;
                const int hh = n >> 6;
                const int dd = 32 * (nc >> 1) + 8 * (l15 >> 2) + 4 * (nc & 1) + (l15 & 3);
                #pragma unroll
                for (int r = 0; r < 4; ++r) {
                    const int m = m0 + 64 * wr + 16 * mr + 4 * g + r;
                    const int bb = m >> 11, tt = m & (NT - 1);
                    dst[(((size_t)bb * NH + hh) * NT + tt) * ND + dd] = f2bf(acc[mr][nc][r]);
                }
            }
        }
    } else {
        // V: direct transposed write; within-64 logical l = 16mr+4g+r sits at
        // position 32*(mr>>1)+8g+4*(mr&1)+r (contiguous in r).
        #pragma unroll
        for (int mr = 0; mr < 4; ++mr) {
            const int m = m0 + 64 * wr + 16 * mr + 4 * g;   // r = 0 base
            const int bb = m >> 11, tt = m & (NT - 1);
            const int tbase = (tt & ~63) + 32 * (mr >> 1) + 8 * g + 4 * (mr & 1);
            #pragma unroll
            for (int nc = 0; nc < 4; ++nc) {
                const int n = n0 + 64 * wc + 16 * nc + l15;
                const int hh = n >> 6, dd = n & 63;
                ushort4_t o;
                #pragma unroll
                for (int r = 0; r < 4; ++r) o[r] = f2bf(acc[mr][nc][r]);
                *(ushort4_t*)&Vt[(((size_t)bb * NH + hh) * ND + dd) * NT + tbase] = o;
            }
        }
    }
}

// ---------------------------------------------------------------------------
// Pass A (windowed) + fused V scaling: block (j, bh) = key strip j;
// q-tiles qt in [j, j+Wt). After the sum, the block scales its own Vt strip
// Vt[bh][*][64j..64j+63] by 1/S in place (strip ownership is exclusive).
// ---------------------------------------------------------------------------
__global__ __launch_bounds__(256, 4) void colstats(const unsigned short* __restrict__ Qh,
                                                   const unsigned short* __restrict__ Kh,
                                                   unsigned short* __restrict__ Vt) {
    __shared__ __align__(16) unsigned short Qs[3][4096];
    __shared__ __align__(16) float Ssum[64];
    const int tid = threadIdx.x;
    const int lane = tid & 63, w = tid >> 6;
    const int g = lane >> 4, l15 = lane & 15;
    const int subrow = lane >> 3;
    const int src_off = (((lane & 7) ^ subrow) << 4);
    const int lin = blockIdx.x + 32 * blockIdx.y;       // 0..1023
    const int xcd = lin & 7, idx = lin >> 3;            // idx 0..127
    const int slot = idx & 3;
    const int j = idx >> 2;                             // 0..31, heavy first
    const int hh = (slot & 1) ? (15 - xcd) : xcd;
    const int bh = ((slot >> 1) << 4) + hh;
    const float slL2 = exp2f(-0.5f * (float)(hh + 1)) * L2E;
    const float C1 = 0.125f * L2E;
    const float s16 = 16.f * slL2;
    const int Wt = WTAB[hh];
    const int qtend = min(32, j + Wt);

    const unsigned short* kr = Kh + ((size_t)bh * NT + 64 * j + 16 * w + l15) * ND;
    const short8 ak0 = frag_g(kr, g, 0), ak1 = frag_g(kr, g, 1);
    const int k0 = 64 * j + 16 * w + 4 * g;

    const char* Qbase = (const char*)(Qh + (size_t)bh * NT * ND);
    auto stage = [&](int buf, int qt) {
        const char* qs = Qbase + (size_t)(64 * qt + 16 * w + subrow) * 128 + src_off;
        char* qd = (char*)&Qs[buf][16 * w * 64];
        GLOAD_LDS(qs, qd);
        GLOAD_LDS(qs + 1024, qd + 1024);
    };

    f32x4 acc = {};
    float rs[4];
    #pragma unroll
    for (int r = 0; r < 4; ++r) rs[r] = (float)r * slL2;

    stage(0, j);
    if (j + 1 < qtend) stage(1, j + 1);
    int cur = 0, nxt = 2;

    for (int qt = j; qt < qtend; ++qt) {
        if (qt + 1 < qtend) asm volatile("s_waitcnt vmcnt(2)" ::: "memory");
        else                asm volatile("s_waitcnt vmcnt(0)" ::: "memory");
        __builtin_amdgcn_s_barrier();
        if (qt + 2 < qtend) stage(nxt, qt + 2);
        const unsigned short* tile = Qs[cur];
        short8 qf[8];
        #pragma unroll
        for (int q4 = 0; q4 < 4; ++q4) {
            qf[2 * q4]     = frag_swz128(tile, 16 * q4 + l15, g, 0);
            qf[2 * q4 + 1] = frag_swz128(tile, 16 * q4 + l15, g, 1);
        }
        float b0 = (float)(k0 - 64 * qt - l15) * slL2;
        const bool mask = (qt == j);
        #pragma unroll
        for (int q4 = 0; q4 < 4; ++q4) {
            f32x4 d = {};
            __builtin_amdgcn_s_setprio(1);
            d = mfma16(ak0, qf[2 * q4], d);
            d = mfma16(ak1, qf[2 * q4 + 1], d);
            __builtin_amdgcn_s_setprio(0);
            #pragma unroll
            for (int r = 0; r < 4; ++r) {
                float e = exp2f(fmaf(d[r], C1, b0 + rs[r]));
                if (mask && (16 * q4 + l15 < 16 * w + 4 * g + r)) e = 0.f;
                acc[r] += e;
            }
            b0 -= s16;
        }
        cur = (cur == 2) ? 0 : cur + 1;
        nxt = (nxt == 2) ? 0 : nxt + 1;
    }
    #pragma unroll
    for (int off = 1; off <= 8; off <<= 1)
        #pragma unroll
        for (int r = 0; r < 4; ++r) acc[r] += __shfl_xor(acc[r], off);
    if (l15 == 0) {
        #pragma unroll
        for (int r = 0; r < 4; ++r) Ssum[16 * w + 4 * g + r] = acc[r];
    }
    __syncthreads();

    // scale this strip of Vt in place: Vt[bh][d][64j + tp], logical t = sigma(tp)
    unsigned short* Vst = Vt + (size_t)bh * ND * NT + 64 * j;
    #pragma unroll
    for (int it = 0; it < 4; ++it) {
        const int c = 256 * it + tid;                  // 0..1023 ushort4-chunks
        const int d = c >> 4;
        const int tp4 = (c & 15) * 4;
        f32x4 s = *(const f32x4*)&Ssum[sigma_p(tp4)];
        unsigned short* p = Vst + (size_t)d * NT + tp4;
        ushort4_t v = *(const ushort4_t*)p;
        ushort4_t o;
        #pragma unroll
        for (int r = 0; r < 4; ++r) o[r] = f2bf(bf2f(v[r]) / s[r]);
        *(ushort4_t*)p = o;
    }
}

// ---------------------------------------------------------------------------
// Pass B (windowed): block (j, bh) = q strip j; k-tiles kt in [j-Wt+1, j].
// V pre-scaled; NBUF=3 counted-vmcnt K/V staging; bf16 att output.
// ---------------------------------------------------------------------------
__global__ __launch_bounds__(256, 3) void attn_pv(const unsigned short* __restrict__ Qh,
                                                  const unsigned short* __restrict__ Kh,
                                                  const unsigned short* __restrict__ Vt,
                                                  unsigned short* __restrict__ att) {
    __shared__ __align__(16) unsigned short Ks[3][4096];
    __shared__ __align__(16) unsigned short Vs[3][4096];
    const int tid = threadIdx.x;
    const int lane = tid & 63, w = tid >> 6;
    const int g = lane >> 4, l15 = lane & 15;
    const int subrow = lane >> 3;
    const int src_off = (((lane & 7) ^ subrow) << 4);
    const int lin = blockIdx.x + 32 * blockIdx.y;       // 0..1023
    const int xcd = lin & 7, idx = lin >> 3;
    const int slot = idx & 3;
    const int j = 31 - (idx >> 2);                      // heavy (large j) first
    const int hh = (slot & 1) ? (15 - xcd) : xcd;
    const int bh = ((slot >> 1) << 4) + hh;
    const int bb = bh >> 4;
    const float slL2 = exp2f(-0.5f * (float)(hh + 1)) * L2E;
    const float C1 = 0.125f * L2E;
    const float s16 = 16.f * slL2;
    const int Wt = WTAB[hh];
    const int ktmin = max(0, j - Wt + 1);

    const int q = 64 * j + 16 * w + l15;
    short8 bq0, bq1;
    {
        const unsigned short* qr = Qh + ((size_t)bh * NT + q) * ND;
        bq0 = frag_g(qr, g, 0);
        bq1 = frag_g(qr, g, 1);
    }
    float rs[4];
    #pragma unroll
    for (int r = 0; r < 4; ++r) rs[r] = (float)r * slL2;

    auto stageKV = [&](int buf, int K0) {
        const char* ksrc = (const char*)Kh + (size_t)((size_t)bh * NT + K0 + 16 * w + subrow) * 128 + src_off;
        char* kdst = (char*)&Ks[buf][16 * w * 64];
        GLOAD_LDS(ksrc, kdst);
        GLOAD_LDS(ksrc + 1024, kdst + 1024);
        const char* vsrc = (const char*)Vt + ((((size_t)bh * ND + 16 * w + subrow) * NT + K0) << 1) + src_off;
        char* vdst = (char*)&Vs[buf][16 * w * 64];
        GLOAD_LDS(vsrc, vdst);
        GLOAD_LDS(vsrc + 8 * NT * 2, vdst + 1024);
    };

    stageKV(0, 64 * ktmin);
    if (ktmin < j) stageKV(1, 64 * (ktmin + 1));
    int cur = 0, nxt = 2;

    f32x4 o[4] = {};

    for (int kt = ktmin; kt <= j; ++kt) {
        if (kt < j) asm volatile("s_waitcnt vmcnt(4)" ::: "memory");
        else        asm volatile("s_waitcnt vmcnt(0)" ::: "memory");
        __builtin_amdgcn_s_barrier();
        if (kt + 2 <= j) stageKV(nxt, 64 * (kt + 2));
        const int K0 = 64 * kt;
        short8 kf[8], vf[8];
        #pragma unroll
        for (int s4 = 0; s4 < 4; ++s4) {
            kf[2 * s4]     = frag_swz128(Ks[cur], 16 * s4 + l15, g, 0);
            kf[2 * s4 + 1] = frag_swz128(Ks[cur], 16 * s4 + l15, g, 1);
            vf[2 * s4]     = frag_swz128(Vs[cur], 16 * s4 + l15, g, 0);
            vf[2 * s4 + 1] = frag_swz128(Vs[cur], 16 * s4 + l15, g, 1);
        }
        f32x4 pacc[4];
        __builtin_amdgcn_s_setprio(1);
        #pragma unroll
        for (int s4 = 0; s4 < 4; ++s4) {
            f32x4 d = {};
            d = mfma16(kf[2 * s4], bq0, d);
            d = mfma16(kf[2 * s4 + 1], bq1, d);
            pacc[s4] = d;
        }
        __builtin_amdgcn_s_setprio(0);
        union { unsigned u[4]; short8 s; } pa[2];
        float b = (float)(K0 + 4 * g - q) * slL2;
        const bool mask = (kt == j);
        #pragma unroll
        for (int s4 = 0; s4 < 4; ++s4) {
            float p[4];
            #pragma unroll
            for (int r = 0; r < 4; ++r)
                p[r] = exp2f(fmaf(pacc[s4][r], C1, b + rs[r]));
            if (mask) {
                #pragma unroll
                for (int r = 0; r < 4; ++r)
                    if (K0 + 16 * s4 + 4 * g + r > q) p[r] = 0.f;
            }
            pa[s4 >> 1].u[2 * (s4 & 1)]     = cvtpk_bf16(p[0], p[1]);
            pa[s4 >> 1].u[2 * (s4 & 1) + 1] = cvtpk_bf16(p[2], p[3]);
            b += s16;
        }
        __builtin_amdgcn_s_setprio(1);
        #pragma unroll
        for (int n = 0; n < 4; ++n) {
            o[n] = mfma16(pa[0].s, vf[2 * n], o[n]);
            o[n] = mfma16(pa[1].s, vf[2 * n + 1], o[n]);
        }
        __builtin_amdgcn_s_setprio(0);
        cur = (cur == 2) ? 0 : cur + 1;
        nxt = (nxt == 2) ? 0 : nxt + 1;
    }
    // att layout: [b][t][h][d], bf16
    #pragma unroll
    for (int n = 0; n < 4; ++n) {
        #pragma unroll
        for (int r = 0; r < 4; ++r) {
            att[(((size_t)bb * NT + 64 * j + 16 * w + 4 * g + r) * NH + hh) * ND + 16 * n + l15] = f2bf(o[n][r]);
        }
    }
}

// ---------------------------------------------------------------------------
// A[row][d] = bf16( sum_h att[row][h][d] )   (att is bf16)
// ---------------------------------------------------------------------------
__global__ __launch_bounds__(256) void headsum(const unsigned short* __restrict__ att,
                                               unsigned short* __restrict__ A) {
    const int row = blockIdx.x * 16 + (threadIdx.x >> 4);
    const int d0 = (threadIdx.x & 15) * 4;
    const unsigned short* p = att + (size_t)row * (NH * ND) + d0;
    f32x4 s = {};
    #pragma unroll
    for (int h = 0; h < NH; ++h) {
        ushort4_t v = *(const ushort4_t*)(p + h * ND);
        #pragma unroll
        for (int jj = 0; jj < 4; ++jj) s[jj] += bf2f(v[jj]);
    }
    ushort4_t o;
    #pragma unroll
    for (int jj = 0; jj < 4; ++jj) o[jj] = f2bf(s[jj]);
    *(ushort4_t*)&A[(size_t)row * ND + d0] = o;
}

// ---------------------------------------------------------------------------
// out[m,n] = x[m,n] + (A @ wo)[m,n]  via MFMA (logical-order fragments)
// ---------------------------------------------------------------------------
__global__ __launch_bounds__(256) void out_proj(const float* __restrict__ x,
                                                const unsigned short* __restrict__ A,
                                                const unsigned short* __restrict__ Wot,
                                                float* __restrict__ out) {
    const int tid = threadIdx.x;
    const int lane = tid & 63, w = tid >> 6;
    const int g = lane >> 4, l15 = lane & 15;
    const int m0 = blockIdx.x * 64, n0 = blockIdx.y * 64;

    const unsigned short* ar = A + (size_t)(m0 + 16 * w + l15) * ND;
    short8 a0 = frag_load(ar, g, 0);
    short8 a1 = frag_load(ar, g, 1);

    f32x4 acc[4] = {};
    #pragma unroll
    for (int ns = 0; ns < 4; ++ns) {
        const unsigned short* br = Wot + (size_t)(n0 + 16 * ns + l15) * ND;
        acc[ns] = mfma16(a0, frag_load(br, g, 0), acc[ns]);
        acc[ns] = mfma16(a1, frag_load(br, g, 1), acc[ns]);
    }
    #pragma unroll
    for (int ns = 0; ns < 4; ++ns) {
        #pragma unroll
        for (int r = 0; r < 4; ++r) {
            int m = m0 + 16 * w + 4 * g + r;
            int n = n0 + 16 * ns + l15;
            out[(size_t)m * NC + n] = x[(size_t)m * NC + n] + acc[ns][r];
        }
    }
}

// ---------------------------------------------------------------------------
extern "C" void kernel_launch(void* const* d_in, const int* in_sizes, int n_in,
                              void* d_out, int out_size, void* d_ws, size_t ws_size,
                              hipStream_t stream) {
    const float* x  = (const float*)d_in[0];
    const float* wq = (const float*)d_in[1];
    const float* wk = (const float*)d_in[2];
    const float* wv = (const float*)d_in[3];
    const float* wo = (const float*)d_in[4];
    float* out = (float*)d_out;

    const size_t MB = 1u << 20;
    const size_t KB = 1u << 10;
    unsigned char* w8 = (unsigned char*)d_ws;
    unsigned short* Xh  = (unsigned short*)(w8);               //  8 MB (sigma k)
    unsigned short* Wta = (unsigned short*)(w8 + 8 * MB);      //  6 MB [3][n][k-sigma]
    unsigned short* Qh  = (unsigned short*)(w8 + 16 * MB);     //  8 MB (sigma d)
    unsigned short* Kh  = (unsigned short*)(w8 + 24 * MB);     //  8 MB (sigma d)
    unsigned short* Vt  = (unsigned short*)(w8 + 32 * MB);     //  8 MB (sigma t)
    unsigned short* att = (unsigned short*)(w8 + 40 * MB);     //  8 MB [b][t][h][d] bf16
    unsigned short* A   = (unsigned short*)(w8 + 48 * MB);     // 512 KB
    unsigned short* Wot = (unsigned short*)(w8 + 48 * MB + 512 * KB);  // 128 KB

    cvt_x<<<(NB * NT * NC) / 1024, 256, 0, stream>>>(x, Xh, (NB * NT * NC) / 4);
    cvtW<<<dim3(16, 16, 4), 256, 0, stream>>>(wq, wk, wv, wo, Wta, Wot);

    gemm_qkv<<<dim3(32, 24), 256, 0, stream>>>(Xh, Wta, Qh, Vt);

    colstats<<<dim3(32, 32), 256, 0, stream>>>(Qh, Kh, Vt);
    attn_pv<<<dim3(32, 32), 256, 0, stream>>>(Qh, Kh, Vt, att);

    headsum<<<(NB * NT) / 16, 256, 0, stream>>>(att, A);
    out_proj<<<dim3(64, 16), 256, 0, stream>>>(x, A, Wot, out);
}

// Round 22
// 125.636 us; speedup vs baseline: 1.0320x; 1.0144x over previous
//
#include <hip/hip_runtime.h>
#include <math.h>

#define NB 2
#define NH 16
#define NT 2048
#define ND 64
#define NC 1024
#define L2E 1.44269504f

typedef __attribute__((ext_vector_type(4))) float f32x4;
typedef __attribute__((ext_vector_type(8))) short short8;
typedef __attribute__((ext_vector_type(4))) short short4_t;
typedef __attribute__((ext_vector_type(8))) unsigned short ushort8;
typedef __attribute__((ext_vector_type(4))) unsigned short ushort4_t;

// per-head attention window in 64-tiles: 1 + ceil(D_h/64), D_h = 40/slL2_h.
__device__ const int WTAB[16] = {2,2,3,3,4,5,6,8,11,15,21,29,32,32,32,32};

#define GLOAD_LDS(gp, lp)                                                \
    __builtin_amdgcn_global_load_lds(                                    \
        (const __attribute__((address_space(1))) void*)(gp),             \
        (__attribute__((address_space(3))) void*)(lp), 16, 0, 0)

// storage permutation: position p holds logical index
// sigma(p) = 4*((p>>3)&3) + (p&3) + 16*((p>>2)&1) + 32*(p>>5)
// fragment (g,h) = one contiguous 16B at ushort offset 8g+32h.
__device__ __forceinline__ int sigma_p(int p) {
    return 4 * ((p >> 3) & 3) + (p & 3) + 16 * ((p >> 2) & 1) + 32 * (p >> 5);
}

__device__ __forceinline__ unsigned short f2bf(float f) {
    unsigned u = __builtin_bit_cast(unsigned, f);
    unsigned r = (u + 0x7FFFu + ((u >> 16) & 1u)) >> 16;
    return (unsigned short)r;
}

__device__ __forceinline__ float bf2f(unsigned short s) {
    return __builtin_bit_cast(float, (unsigned)s << 16);
}

__device__ __forceinline__ unsigned cvtpk_bf16(float lo, float hi) {
    unsigned r;
    asm("v_cvt_pk_bf16_f32 %0, %1, %2" : "=v"(r) : "v"(lo), "v"(hi));
    return r;
}

__device__ __forceinline__ f32x4 mfma16(short8 a, short8 b, f32x4 c) {
    return __builtin_amdgcn_mfma_f32_16x16x32_bf16(a, b, c, 0, 0, 0);
}

// split-fragment load (out_proj path, logical order)
__device__ __forceinline__ short8 frag_load(const unsigned short* rowp, int g, int half) {
    short8 v;
    short4_t lo = *(const short4_t*)(rowp + 4 * g + 32 * half);
    short4_t hi = *(const short4_t*)(rowp + 4 * g + 16 + 32 * half);
    #pragma unroll
    for (int j = 0; j < 4; ++j) { v[j] = lo[j]; v[4 + j] = hi[j]; }
    return v;
}

// sigma-stored global row: fragment = single 16B load
__device__ __forceinline__ short8 frag_g(const unsigned short* rowp, int g, int half) {
    return *(const short8*)(rowp + 8 * g + 32 * half);
}

// sigma-stored LDS tile, 128B rows (64 k): chunk XOR by (row&7)
__device__ __forceinline__ short8 frag_swz128(const unsigned short* tile, int row, int g, int half) {
    const char* p = (const char*)tile + row * 128 + (((g + 4 * half) ^ (row & 7)) << 4);
    return *(const short8*)p;
}

// sigma-stored LDS tile, 64B rows (32 k): chunk XOR by ((row>>1)&3)
__device__ __forceinline__ short8 frag_swz32(const unsigned short* tile, int row, int g) {
    const char* p = (const char*)tile + row * 64 + (((g ^ ((row >> 1) & 3))) << 4);
    return *(const short8*)p;
}

// ---------------------------------------------------------------------------
// x f32 -> bf16 with sigma permutation of each 64-dim block
// ---------------------------------------------------------------------------
__global__ __launch_bounds__(256) void cvt_x(const float* __restrict__ src,
                                             unsigned short* __restrict__ dst, int n4) {
    int i = blockIdx.x * 256 + threadIdx.x;
    if (i >= n4) return;
    const int blk = i >> 4, c4 = i & 15;
    const int gg = (c4 >> 1) & 3, bb = c4 & 1, hh = c4 >> 3;
    f32x4 v = ((const f32x4*)src)[blk * 16 + gg + 4 * bb + 8 * hh];
    ushort4_t o;
    #pragma unroll
    for (int j = 0; j < 4; ++j) o[j] = f2bf(v[j]);
    ((ushort4_t*)dst)[i] = o;
}

// ---------------------------------------------------------------------------
// weights: z=0..2 -> wq/wk/wv f32 [k][n] -> bf16 [n][k-sigma];
// z=3 (x-block 0 only) -> wo f32 [64][1024] -> bf16 [n][k] logical.
// ---------------------------------------------------------------------------
__global__ __launch_bounds__(256) void cvtW(const float* __restrict__ w0,
                                            const float* __restrict__ w1,
                                            const float* __restrict__ w2,
                                            const float* __restrict__ w3,
                                            unsigned short* __restrict__ Wt_all,
                                            unsigned short* __restrict__ Wot) {
    __shared__ __align__(16) float T[64][68];
    const int z = blockIdx.z;
    const int tid = threadIdx.x;
    if (z == 3) {
        if (blockIdx.x != 0) return;
        const int n0 = blockIdx.y * 64;
        #pragma unroll
        for (int p = 0; p < 4; ++p) {
            int r = 16 * p + (tid >> 4);
            int c = (tid & 15) * 4;
            *(f32x4*)&T[r][c] = *(const f32x4*)&w3[(size_t)r * NC + n0 + c];
        }
        __syncthreads();
        const int nr = tid >> 2, kc = (tid & 3) * 16;
        ushort8 o0, o1;
        #pragma unroll
        for (int j = 0; j < 8; ++j) { o0[j] = f2bf(T[kc + j][nr]); o1[j] = f2bf(T[kc + 8 + j][nr]); }
        unsigned short* q = Wot + (size_t)(n0 + nr) * ND + kc;
        *(ushort8*)q       = o0;
        *(ushort8*)(q + 8) = o1;
        return;
    }
    const float* W = (z == 0) ? w0 : ((z == 1) ? w1 : w2);
    unsigned short* Wt = Wt_all + (size_t)z * NC * NC;
    const int k0 = blockIdx.x * 64, n0 = blockIdx.y * 64;
    #pragma unroll
    for (int p = 0; p < 4; ++p) {
        int r = 16 * p + (tid >> 4);
        int c = (tid & 15) * 4;
        *(f32x4*)&T[r][c] = *(const f32x4*)&W[(size_t)(k0 + r) * NC + n0 + c];
    }
    __syncthreads();
    const int nr = tid >> 2, kc = (tid & 3) * 16;
    ushort8 o0, o1;
    #pragma unroll
    for (int j = 0; j < 8; ++j) o0[j] = f2bf(T[sigma_p(kc + j)][nr]);
    #pragma unroll
    for (int j = 0; j < 8; ++j) o1[j] = f2bf(T[sigma_p(kc + 8 + j)][nr]);
    unsigned short* q = Wt + (size_t)(n0 + nr) * NC + k0 + kc;
    *(ushort8*)q       = o0;
    *(ushort8*)(q + 8) = o1;
}

// ---------------------------------------------------------------------------
// bf16 MFMA GEMM, 128x128 tile, 4 waves, K-step 32, NBUF=3 COUNTED pipeline.
// Single launch for Q,K,V. Q/K -> sigma-d [bh][t][d']; V -> Vt[bh][d][t-sigma].
// ---------------------------------------------------------------------------
__global__ __launch_bounds__(256, 3) void gemm_qkv(const unsigned short* __restrict__ Xh,
                                                   const unsigned short* __restrict__ Wt_all,
                                                   unsigned short* __restrict__ qk_dst,
                                                   unsigned short* __restrict__ Vt) {
    __shared__ __align__(16) unsigned short Xs[3][4096];
    __shared__ __align__(16) unsigned short Ws[3][4096];
    const int tid = threadIdx.x;
    const int lane = tid & 63, w = tid >> 6;
    const int g = lane >> 4, l15 = lane & 15;
    const int wr = w >> 1, wc = w & 1;
    const int m0 = blockIdx.x * 128;
    const int which = blockIdx.y >> 3;
    const int n0 = (blockIdx.y & 7) * 128;
    const unsigned short* Wt = Wt_all + (size_t)which * NC * NC;

    const int sr[2] = { (0 * 256 + w * 64 + lane) >> 2, (1 * 256 + w * 64 + lane) >> 2 };
    const int sc[2] = { ((0 * 256 + w * 64 + lane) & 3) ^ ((sr[0] >> 1) & 3),
                        ((1 * 256 + w * 64 + lane) & 3) ^ ((sr[1] >> 1) & 3) };

    f32x4 acc[4][4] = {};

    auto stage = [&](int buf, int kt) {
        const size_t kb = (size_t)kt * 64;
        #pragma unroll
        for (int i = 0; i < 2; ++i) {
            const char* xs = (const char*)Xh + (size_t)(m0 + sr[i]) * 2048 + kb + (sc[i] << 4);
            GLOAD_LDS(xs, (char*)&Xs[buf][(i * 256 + w * 64) * 8]);
            const char* ws = (const char*)Wt + (size_t)(n0 + sr[i]) * 2048 + kb + (sc[i] << 4);
            GLOAD_LDS(ws, (char*)&Ws[buf][(i * 256 + w * 64) * 8]);
        }
    };

    stage(0, 0);
    stage(1, 1);
    int cur = 0, nxt = 2;

    for (int kt = 0; kt < 32; ++kt) {
        if (kt < 31) asm volatile("s_waitcnt vmcnt(4)" ::: "memory");
        else         asm volatile("s_waitcnt vmcnt(0)" ::: "memory");
        __builtin_amdgcn_s_barrier();
        if (kt + 2 < 32) stage(nxt, kt + 2);
        short8 a[4], b[4];
        #pragma unroll
        for (int mr = 0; mr < 4; ++mr)
            a[mr] = frag_swz32(Xs[cur], 64 * wr + 16 * mr + l15, g);
        #pragma unroll
        for (int nc = 0; nc < 4; ++nc)
            b[nc] = frag_swz32(Ws[cur], 64 * wc + 16 * nc + l15, g);
        __builtin_amdgcn_s_setprio(1);
        #pragma unroll
        for (int mr = 0; mr < 4; ++mr)
            #pragma unroll
            for (int nc = 0; nc < 4; ++nc)
                acc[mr][nc] = mfma16(a[mr], b[nc], acc[mr][nc]);
        __builtin_amdgcn_s_setprio(0);
        cur = (cur == 2) ? 0 : cur + 1;
        nxt = (nxt == 2) ? 0 : nxt + 1;
    }

    if (which < 2) {
        unsigned short* dst = qk_dst + (size_t)which * (NB * NH * NT * ND);
        #pragma unroll
        for (int mr = 0; mr < 4; ++mr) {
            #pragma unroll
            for (int nc = 0; nc < 4; ++nc) {
                const int n = n0 + 64 * wc + 16 * nc + l15;
                const int hh = n >> 6;
                const int dd = 32 * (nc >> 1) + 8 * (l15 >> 2) + 4 * (nc & 1) + (l15 & 3);
                #pragma unroll
                for (int r = 0; r < 4; ++r) {
                    const int m = m0 + 64 * wr + 16 * mr + 4 * g + r;
                    const int bb = m >> 11, tt = m & (NT - 1);
                    dst[(((size_t)bb * NH + hh) * NT + tt) * ND + dd] = f2bf(acc[mr][nc][r]);
                }
            }
        }
    } else {
        #pragma unroll
        for (int mr = 0; mr < 4; ++mr) {
            const int m = m0 + 64 * wr + 16 * mr + 4 * g;
            const int bb = m >> 11, tt = m & (NT - 1);
            const int tbase = (tt & ~63) + 32 * (mr >> 1) + 8 * g + 4 * (mr & 1);
            #pragma unroll
            for (int nc = 0; nc < 4; ++nc) {
                const int n = n0 + 64 * wc + 16 * nc + l15;
                const int hh = n >> 6, dd = n & 63;
                ushort4_t o;
                #pragma unroll
                for (int r = 0; r < 4; ++r) o[r] = f2bf(acc[mr][nc][r]);
                *(ushort4_t*)&Vt[(((size_t)bb * NH + hh) * ND + dd) * NT + tbase] = o;
            }
        }
    }
}

// ---------------------------------------------------------------------------
// Pass A (windowed) + fused V scaling: block (j, bh) = key strip j;
// q-tiles qt in [j, j+Wt). After the sum, the block scales its own Vt strip.
// ---------------------------------------------------------------------------
__global__ __launch_bounds__(256, 4) void colstats(const unsigned short* __restrict__ Qh,
                                                   const unsigned short* __restrict__ Kh,
                                                   unsigned short* __restrict__ Vt) {
    __shared__ __align__(16) unsigned short Qs[3][4096];
    __shared__ __align__(16) float Ssum[64];
    const int tid = threadIdx.x;
    const int lane = tid & 63, w = tid >> 6;
    const int g = lane >> 4, l15 = lane & 15;
    const int subrow = lane >> 3;
    const int src_off = (((lane & 7) ^ subrow) << 4);
    const int lin = blockIdx.x + 32 * blockIdx.y;       // 0..1023
    const int xcd = lin & 7, idx = lin >> 3;            // idx 0..127
    const int slot = idx & 3;
    const int j = idx >> 2;                             // 0..31, heavy first
    const int hh = (slot & 1) ? (15 - xcd) : xcd;
    const int bh = ((slot >> 1) << 4) + hh;
    const float slL2 = exp2f(-0.5f * (float)(hh + 1)) * L2E;
    const float C1 = 0.125f * L2E;
    const float s16 = 16.f * slL2;
    const int Wt = WTAB[hh];
    const int qtend = min(32, j + Wt);

    const unsigned short* kr = Kh + ((size_t)bh * NT + 64 * j + 16 * w + l15) * ND;
    const short8 ak0 = frag_g(kr, g, 0), ak1 = frag_g(kr, g, 1);
    const int k0 = 64 * j + 16 * w + 4 * g;

    const char* Qbase = (const char*)(Qh + (size_t)bh * NT * ND);
    auto stage = [&](int buf, int qt) {
        const char* qs = Qbase + (size_t)(64 * qt + 16 * w + subrow) * 128 + src_off;
        char* qd = (char*)&Qs[buf][16 * w * 64];
        GLOAD_LDS(qs, qd);
        GLOAD_LDS(qs + 1024, qd + 1024);
    };

    f32x4 acc = {};
    float rs[4];
    #pragma unroll
    for (int r = 0; r < 4; ++r) rs[r] = (float)r * slL2;

    stage(0, j);
    if (j + 1 < qtend) stage(1, j + 1);
    int cur = 0, nxt = 2;

    for (int qt = j; qt < qtend; ++qt) {
        if (qt + 1 < qtend) asm volatile("s_waitcnt vmcnt(2)" ::: "memory");
        else                asm volatile("s_waitcnt vmcnt(0)" ::: "memory");
        __builtin_amdgcn_s_barrier();
        if (qt + 2 < qtend) stage(nxt, qt + 2);
        const unsigned short* tile = Qs[cur];
        short8 qf[8];
        #pragma unroll
        for (int q4 = 0; q4 < 4; ++q4) {
            qf[2 * q4]     = frag_swz128(tile, 16 * q4 + l15, g, 0);
            qf[2 * q4 + 1] = frag_swz128(tile, 16 * q4 + l15, g, 1);
        }
        float b0 = (float)(k0 - 64 * qt - l15) * slL2;
        const bool mask = (qt == j);
        #pragma unroll
        for (int q4 = 0; q4 < 4; ++q4) {
            f32x4 d = {};
            __builtin_amdgcn_s_setprio(1);
            d = mfma16(ak0, qf[2 * q4], d);
            d = mfma16(ak1, qf[2 * q4 + 1], d);
            __builtin_amdgcn_s_setprio(0);
            #pragma unroll
            for (int r = 0; r < 4; ++r) {
                float e = exp2f(fmaf(d[r], C1, b0 + rs[r]));
                if (mask && (16 * q4 + l15 < 16 * w + 4 * g + r)) e = 0.f;
                acc[r] += e;
            }
            b0 -= s16;
        }
        cur = (cur == 2) ? 0 : cur + 1;
        nxt = (nxt == 2) ? 0 : nxt + 1;
    }
    #pragma unroll
    for (int off = 1; off <= 8; off <<= 1)
        #pragma unroll
        for (int r = 0; r < 4; ++r) acc[r] += __shfl_xor(acc[r], off);
    if (l15 == 0) {
        #pragma unroll
        for (int r = 0; r < 4; ++r) Ssum[16 * w + 4 * g + r] = acc[r];
    }
    __syncthreads();

    unsigned short* Vst = Vt + (size_t)bh * ND * NT + 64 * j;
    #pragma unroll
    for (int it = 0; it < 4; ++it) {
        const int c = 256 * it + tid;
        const int d = c >> 4;
        const int tp4 = (c & 15) * 4;
        f32x4 s = *(const f32x4*)&Ssum[sigma_p(tp4)];
        unsigned short* p = Vst + (size_t)d * NT + tp4;
        ushort4_t v = *(const ushort4_t*)p;
        ushort4_t o;
        #pragma unroll
        for (int r = 0; r < 4; ++r) o[r] = f2bf(bf2f(v[r]) / s[r]);
        *(ushort4_t*)p = o;
    }
}

// ---------------------------------------------------------------------------
// Pass B (windowed, heavy-head k-range split): grid 32x44 = 1408 blocks.
//   lin <  384: SECONDARY half of heavy heads (hh>=10): kt in [mid, j]
//   lin <  768: PRIMARY  half of heavy heads:           kt in [ktmin, mid)
//   lin >= 768: light heads (hh<10), full range [ktmin, j]
// Secondary writes att2 (zeros if empty); primary/light write att.
// ---------------------------------------------------------------------------
__global__ __launch_bounds__(256, 3) void attn_pv(const unsigned short* __restrict__ Qh,
                                                  const unsigned short* __restrict__ Kh,
                                                  const unsigned short* __restrict__ Vt,
                                                  unsigned short* __restrict__ att,
                                                  unsigned short* __restrict__ att2) {
    __shared__ __align__(16) unsigned short Ks[3][4096];
    __shared__ __align__(16) unsigned short Vs[3][4096];
    const int tid = threadIdx.x;
    const int lane = tid & 63, w = tid >> 6;
    const int g = lane >> 4, l15 = lane & 15;
    const int subrow = lane >> 3;
    const int src_off = (((lane & 7) ^ subrow) << 4);
    const int lin = blockIdx.x + 32 * blockIdx.y;       // 0..1407

    int j, hh, bh, half;                                // half: 1=sec, 0=pri, -1=light
    if (lin < 768) {
        half = (lin < 384) ? 1 : 0;
        const int v = (lin < 384) ? lin : (lin - 384);
        j = 31 - (v / 12);
        const int r = v % 12;
        hh = 10 + (r % 6);
        bh = (r / 6) * 16 + hh;
    } else {
        half = -1;
        const int v = lin - 768;
        j = 31 - (v / 20);
        const int r = v % 20;
        hh = r % 10;
        bh = (r / 10) * 16 + hh;
    }
    const int bb = bh >> 4;
    const float slL2 = exp2f(-0.5f * (float)(hh + 1)) * L2E;
    const float C1 = 0.125f * L2E;
    const float s16 = 16.f * slL2;
    const int Wt = WTAB[hh];
    const int ktmin = max(0, j - Wt + 1);

    int ktA, ktB;
    unsigned short* dst;
    if (half < 0) {
        ktA = ktmin; ktB = j; dst = att;
    } else {
        const int range = j - ktmin + 1;
        const int nlow = (range + 1) >> 1;
        if (half == 0) { ktA = ktmin;        ktB = ktmin + nlow - 1; dst = att; }
        else           { ktA = ktmin + nlow; ktB = j;                dst = att2; }
    }

    const int q = 64 * j + 16 * w + l15;
    short8 bq0, bq1;
    {
        const unsigned short* qr = Qh + ((size_t)bh * NT + q) * ND;
        bq0 = frag_g(qr, g, 0);
        bq1 = frag_g(qr, g, 1);
    }
    float rs[4];
    #pragma unroll
    for (int r = 0; r < 4; ++r) rs[r] = (float)r * slL2;

    auto stageKV = [&](int buf, int K0) {
        const char* ksrc = (const char*)Kh + (size_t)((size_t)bh * NT + K0 + 16 * w + subrow) * 128 + src_off;
        char* kdst = (char*)&Ks[buf][16 * w * 64];
        GLOAD_LDS(ksrc, kdst);
        GLOAD_LDS(ksrc + 1024, kdst + 1024);
        const char* vsrc = (const char*)Vt + ((((size_t)bh * ND + 16 * w + subrow) * NT + K0) << 1) + src_off;
        char* vdst = (char*)&Vs[buf][16 * w * 64];
        GLOAD_LDS(vsrc, vdst);
        GLOAD_LDS(vsrc + 8 * NT * 2, vdst + 1024);
    };

    f32x4 o[4] = {};

    if (ktA <= ktB) {
        stageKV(0, 64 * ktA);
        if (ktA < ktB) stageKV(1, 64 * (ktA + 1));
        int cur = 0, nxt = 2;

        for (int kt = ktA; kt <= ktB; ++kt) {
            if (kt < ktB) asm volatile("s_waitcnt vmcnt(4)" ::: "memory");
            else          asm volatile("s_waitcnt vmcnt(0)" ::: "memory");
            __builtin_amdgcn_s_barrier();
            if (kt + 2 <= ktB) stageKV(nxt, 64 * (kt + 2));
            const int K0 = 64 * kt;
            short8 kf[8], vf[8];
            #pragma unroll
            for (int s4 = 0; s4 < 4; ++s4) {
                kf[2 * s4]     = frag_swz128(Ks[cur], 16 * s4 + l15, g, 0);
                kf[2 * s4 + 1] = frag_swz128(Ks[cur], 16 * s4 + l15, g, 1);
                vf[2 * s4]     = frag_swz128(Vs[cur], 16 * s4 + l15, g, 0);
                vf[2 * s4 + 1] = frag_swz128(Vs[cur], 16 * s4 + l15, g, 1);
            }
            f32x4 pacc[4];
            __builtin_amdgcn_s_setprio(1);
            #pragma unroll
            for (int s4 = 0; s4 < 4; ++s4) {
                f32x4 d = {};
                d = mfma16(kf[2 * s4], bq0, d);
                d = mfma16(kf[2 * s4 + 1], bq1, d);
                pacc[s4] = d;
            }
            __builtin_amdgcn_s_setprio(0);
            union { unsigned u[4]; short8 s; } pa[2];
            float b = (float)(K0 + 4 * g - q) * slL2;
            const bool mask = (kt == j);
            #pragma unroll
            for (int s4 = 0; s4 < 4; ++s4) {
                float p[4];
                #pragma unroll
                for (int r = 0; r < 4; ++r)
                    p[r] = exp2f(fmaf(pacc[s4][r], C1, b + rs[r]));
                if (mask) {
                    #pragma unroll
                    for (int r = 0; r < 4; ++r)
                        if (K0 + 16 * s4 + 4 * g + r > q) p[r] = 0.f;
                }
                pa[s4 >> 1].u[2 * (s4 & 1)]     = cvtpk_bf16(p[0], p[1]);
                pa[s4 >> 1].u[2 * (s4 & 1) + 1] = cvtpk_bf16(p[2], p[3]);
                b += s16;
            }
            __builtin_amdgcn_s_setprio(1);
            #pragma unroll
            for (int n = 0; n < 4; ++n) {
                o[n] = mfma16(pa[0].s, vf[2 * n], o[n]);
                o[n] = mfma16(pa[1].s, vf[2 * n + 1], o[n]);
            }
            __builtin_amdgcn_s_setprio(0);
            cur = (cur == 2) ? 0 : cur + 1;
            nxt = (nxt == 2) ? 0 : nxt + 1;
        }
    }
    // partial/full output, [b][t][h][d] bf16 (zeros if range empty)
    #pragma unroll
    for (int n = 0; n < 4; ++n) {
        #pragma unroll
        for (int r = 0; r < 4; ++r) {
            dst[(((size_t)bb * NT + 64 * j + 16 * w + 4 * g + r) * NH + hh) * ND + 16 * n + l15] = f2bf(o[n][r]);
        }
    }
}

// ---------------------------------------------------------------------------
// A[row][d] = bf16( sum_h att[row][h][d] + (h>=10 ? att2[row][h][d] : 0) )
// ---------------------------------------------------------------------------
__global__ __launch_bounds__(256) void headsum(const unsigned short* __restrict__ att,
                                               const unsigned short* __restrict__ att2,
                                               unsigned short* __restrict__ A) {
    const int row = blockIdx.x * 16 + (threadIdx.x >> 4);
    const int d0 = (threadIdx.x & 15) * 4;
    const unsigned short* p  = att  + (size_t)row * (NH * ND) + d0;
    const unsigned short* p2 = att2 + (size_t)row * (NH * ND) + d0;
    f32x4 s = {};
    #pragma unroll
    for (int h = 0; h < NH; ++h) {
        ushort4_t v = *(const ushort4_t*)(p + h * ND);
        #pragma unroll
        for (int jj = 0; jj < 4; ++jj) s[jj] += bf2f(v[jj]);
    }
    #pragma unroll
    for (int h = 10; h < NH; ++h) {
        ushort4_t v = *(const ushort4_t*)(p2 + h * ND);
        #pragma unroll
        for (int jj = 0; jj < 4; ++jj) s[jj] += bf2f(v[jj]);
    }
    ushort4_t o;
    #pragma unroll
    for (int jj = 0; jj < 4; ++jj) o[jj] = f2bf(s[jj]);
    *(ushort4_t*)&A[(size_t)row * ND + d0] = o;
}

// ---------------------------------------------------------------------------
// out[m,n] = x[m,n] + (A @ wo)[m,n]  via MFMA (logical-order fragments)
// ---------------------------------------------------------------------------
__global__ __launch_bounds__(256) void out_proj(const float* __restrict__ x,
                                                const unsigned short* __restrict__ A,
                                                const unsigned short* __restrict__ Wot,
                                                float* __restrict__ out) {
    const int tid = threadIdx.x;
    const int lane = tid & 63, w = tid >> 6;
    const int g = lane >> 4, l15 = lane & 15;
    const int m0 = blockIdx.x * 64, n0 = blockIdx.y * 64;

    const unsigned short* ar = A + (size_t)(m0 + 16 * w + l15) * ND;
    short8 a0 = frag_load(ar, g, 0);
    short8 a1 = frag_load(ar, g, 1);

    f32x4 acc[4] = {};
    #pragma unroll
    for (int ns = 0; ns < 4; ++ns) {
        const unsigned short* br = Wot + (size_t)(n0 + 16 * ns + l15) * ND;
        acc[ns] = mfma16(a0, frag_load(br, g, 0), acc[ns]);
        acc[ns] = mfma16(a1, frag_load(br, g, 1), acc[ns]);
    }
    #pragma unroll
    for (int ns = 0; ns < 4; ++ns) {
        #pragma unroll
        for (int r = 0; r < 4; ++r) {
            int m = m0 + 16 * w + 4 * g + r;
            int n = n0 + 16 * ns + l15;
            out[(size_t)m * NC + n] = x[(size_t)m * NC + n] + acc[ns][r];
        }
    }
}

// ---------------------------------------------------------------------------
extern "C" void kernel_launch(void* const* d_in, const int* in_sizes, int n_in,
                              void* d_out, int out_size, void* d_ws, size_t ws_size,
                              hipStream_t stream) {
    const float* x  = (const float*)d_in[0];
    const float* wq = (const float*)d_in[1];
    const float* wk = (const float*)d_in[2];
    const float* wv = (const float*)d_in[3];
    const float* wo = (const float*)d_in[4];
    float* out = (float*)d_out;

    const size_t MB = 1u << 20;
    const size_t KB = 1u << 10;
    unsigned char* w8 = (unsigned char*)d_ws;
    unsigned short* Xh   = (unsigned short*)(w8);               //  8 MB (sigma k)
    unsigned short* Wta  = (unsigned short*)(w8 + 8 * MB);      //  6 MB [3][n][k-sigma]
    unsigned short* Qh   = (unsigned short*)(w8 + 16 * MB);     //  8 MB (sigma d)
    unsigned short* Kh   = (unsigned short*)(w8 + 24 * MB);     //  8 MB (sigma d)
    unsigned short* Vt   = (unsigned short*)(w8 + 32 * MB);     //  8 MB (sigma t)
    unsigned short* att  = (unsigned short*)(w8 + 40 * MB);     //  8 MB bf16
    unsigned short* att2 = (unsigned short*)(w8 + 48 * MB);     //  8 MB bf16 (heavy heads)
    unsigned short* A    = (unsigned short*)(w8 + 56 * MB);     // 512 KB
    unsigned short* Wot  = (unsigned short*)(w8 + 56 * MB + 512 * KB);  // 128 KB

    cvt_x<<<(NB * NT * NC) / 1024, 256, 0, stream>>>(x, Xh, (NB * NT * NC) / 4);
    cvtW<<<dim3(16, 16, 4), 256, 0, stream>>>(wq, wk, wv, wo, Wta, Wot);

    gemm_qkv<<<dim3(32, 24), 256, 0, stream>>>(Xh, Wta, Qh, Vt);

    colstats<<<dim3(32, 32), 256, 0, stream>>>(Qh, Kh, Vt);
    attn_pv<<<dim3(32, 44), 256, 0, stream>>>(Qh, Kh, Vt, att, att2);

    headsum<<<(NB * NT) / 16, 256, 0, stream>>>(att, att2, A);
    out_proj<<<dim3(64, 16), 256, 0, stream>>>(x, A, Wot, out);
}